// Round 1
// baseline (728.833 us; speedup 1.0000x reference)
//
#include <hip/hip_runtime.h>

#define D_IN 256
#define D_HALF 128

typedef __attribute__((ext_vector_type(8))) short short8;
typedef __attribute__((ext_vector_type(4))) float float4v;

__device__ __forceinline__ unsigned short f2bf(float f) {
    union { float f; unsigned u; } v; v.f = f;
    unsigned r = v.u + 0x7FFF + ((v.u >> 16) & 1);   // RNE
    return (unsigned short)(r >> 16);
}
__device__ __forceinline__ float bflo(unsigned u) { union { unsigned u; float f; } v; v.u = u << 16; return v.f; }
__device__ __forceinline__ float bfhi(unsigned u) { union { unsigned u; float f; } v; v.u = u & 0xffff0000u; return v.f; }

__device__ __forceinline__ void async16(const void* g, void* l) {
    __builtin_amdgcn_global_load_lds(
        (const __attribute__((address_space(1))) unsigned int*)g,
        (__attribute__((address_space(3))) unsigned int*)l, 16, 0, 0);
}

// ---------------- CSR build ----------------

#define FB_SH 14            // bucket = 16384 adj slots = 64 KB write window
#define FB_NB 512           // max buckets supported (2E <= 512*16384 = 8.4M)

__global__ void zero_kernel(int* __restrict__ cnt, int* __restrict__ ctr,
                            int* __restrict__ gcnt, int M) {
    int i = blockIdx.x * blockDim.x + threadIdx.x;
    if (i < M) { cnt[i] = 0; ctr[i] = 0; }
    if (i < FB_NB) gcnt[i] = 0;
}

__global__ void hist_kernel(const int* __restrict__ col, const int* __restrict__ row,
                            int* __restrict__ cnt, int N, int E) {
    int i = blockIdx.x * blockDim.x + threadIdx.x;
    if (i < E) {
        atomicAdd(&cnt[col[i]], 1);
        atomicAdd(&cnt[N + row[i]], 1);
    }
}

__global__ void inv_kernel(const int* __restrict__ cnt,
                           float* __restrict__ inv_in, float* __restrict__ inv_out, int N) {
    int i = blockIdx.x * blockDim.x + threadIdx.x;
    if (i < N) {
        inv_in[i]  = rsqrtf((float)(cnt[i] + 1));
        inv_out[i] = rsqrtf((float)(cnt[N + i] + 1));
    }
}

__global__ void scan1_kernel(const int* __restrict__ cnt, int* __restrict__ offs,
                             int* __restrict__ blksum, int M) {
    __shared__ int s[256];
    int i = blockIdx.x * 256 + threadIdx.x;
    int v = (i < M) ? cnt[i] : 0;
    s[threadIdx.x] = v;
    __syncthreads();
    for (int d = 1; d < 256; d <<= 1) {
        int t = (threadIdx.x >= d) ? s[threadIdx.x - d] : 0;
        __syncthreads();
        s[threadIdx.x] += t;
        __syncthreads();
    }
    if (i < M) offs[i] = s[threadIdx.x] - v;
    if (threadIdx.x == 255) blksum[blockIdx.x] = s[255];
}

__global__ void scan2_kernel(int* __restrict__ blksum, int nb) {
    __shared__ int s[1024];
    int v = (threadIdx.x < nb) ? blksum[threadIdx.x] : 0;
    s[threadIdx.x] = v;
    __syncthreads();
    for (int d = 1; d < 1024; d <<= 1) {
        int t = (threadIdx.x >= d) ? s[threadIdx.x - d] : 0;
        __syncthreads();
        s[threadIdx.x] += t;
        __syncthreads();
    }
    if (threadIdx.x < nb) blksum[threadIdx.x] = s[threadIdx.x] - v;
}

__global__ void scan3_kernel(int* __restrict__ offs, const int* __restrict__ blksum, int M) {
    int i = blockIdx.x * 256 + threadIdx.x;
    if (i < M) offs[i] += blksum[blockIdx.x];
}

// Pass A: compute (pos,val) scatter items, partition them into buckets of
// 16384 adj slots each via LDS histogram + block-aggregated global atomics.
// Staging layout is fixed: bucket b owns staging[b<<FB_SH .. (b+1)<<FB_SH)
// because every adj position in [0,2E) occurs exactly once.
// 2048 edges (4096 items) per block.
__global__ void partition_kernel(const int* __restrict__ col, const int* __restrict__ row,
                                 const int* __restrict__ offs, int* __restrict__ ctr,
                                 int* __restrict__ gcnt, uint2* __restrict__ staging,
                                 int N, int E) {
    __shared__ int scnt[FB_NB];
    __shared__ int sbase[FB_NB];
    const int tid = threadIdx.x;
    #pragma unroll
    for (int b = 0; b < FB_NB / 256; ++b) scnt[b * 256 + tid] = 0;
    __syncthreads();

    int pos[16], val[16], rnk[16];
    const int base = blockIdx.x * 2048;
    #pragma unroll
    for (int j = 0; j < 8; ++j) {
        int e = base + j * 256 + tid;
        if (e < E) {
            int c = col[e], r = row[e];
            int pf = offs[c] + atomicAdd(&ctr[c], 1);
            int pb = offs[N + r] + atomicAdd(&ctr[N + r], 1);
            pos[2 * j]     = pf; val[2 * j]     = r;
            pos[2 * j + 1] = pb; val[2 * j + 1] = c;
        } else {
            pos[2 * j] = -1; pos[2 * j + 1] = -1;
        }
    }
    #pragma unroll
    for (int k = 0; k < 16; ++k)
        if (pos[k] >= 0) rnk[k] = atomicAdd(&scnt[pos[k] >> FB_SH], 1);
    __syncthreads();
    #pragma unroll
    for (int b = 0; b < FB_NB / 256; ++b) {
        int idx = b * 256 + tid;
        int c = scnt[idx];
        sbase[idx] = c ? atomicAdd(&gcnt[idx], c) : 0;
    }
    __syncthreads();
    #pragma unroll
    for (int k = 0; k < 16; ++k) {
        if (pos[k] >= 0) {
            int bk = pos[k] >> FB_SH;
            staging[((size_t)bk << FB_SH) + sbase[bk] + rnk[k]] =
                make_uint2((unsigned)pos[k], (unsigned)val[k]);
        }
    }
}

// Pass B: one block per bucket. Coalesced staging read; scatter writes are
// confined to this block's exclusive 64 KB adj window -> full-line writeback.
__global__ void scatter_kernel(const uint2* __restrict__ staging, int* __restrict__ adj,
                               int twoE) {
    const int start = blockIdx.x << FB_SH;
    const int cnt = min(1 << FB_SH, twoE - start);
    for (int i = threadIdx.x; i < cnt; i += 256) {
        uint2 it = staging[(size_t)start + i];
        adj[it.x] = (int)it.y;
    }
}

// ---------------- cast x -> bf16, [Wf;Wb] -> bf16 ----------------

__global__ void cast_kernel(const float* __restrict__ x, const float* __restrict__ Wf,
                            const float* __restrict__ Wb, unsigned short* __restrict__ xb,
                            unsigned short* __restrict__ wcat, int n4) {
    int i = blockIdx.x * blockDim.x + threadIdx.x;
    const int w4 = (2 * D_HALF * D_IN) / 4;  // 16384 float4s of Wcat
    if (i < n4) {
        float4 v = ((const float4*)x)[i];
        ushort4 o = { f2bf(v.x), f2bf(v.y), f2bf(v.z), f2bf(v.w) };
        ((ushort4*)xb)[i] = o;
    } else if (i < n4 + w4) {
        int j = i - n4;
        int elem = j * 4;
        const float* src = (elem < D_HALF * D_IN) ? (Wf + elem) : (Wb + (elem - D_HALF * D_IN));
        float4 v = *(const float4*)src;
        ushort4 o = { f2bf(v.x), f2bf(v.y), f2bf(v.z), f2bf(v.w) };
        ((ushort4*)wcat)[j] = o;
    }
}

// ---------------- bf16 MFMA GEMM: zb[m][n] = sum_k xb[m][k] * wcat[n][k] ----------------
// 128x128 tile, BK=32, 256 threads (4 waves, each 64x64), 16x16x32 MFMA.
// LDS XOR swizzle: granule (16B) of (row m, kgran g) stored at m*64B + (g ^ ((m>>1)&3))*16B.

#define BM 128
#define BN 128
#define BK 32

__global__ void gemm_mfma_kernel(const unsigned short* __restrict__ xb,
                                 const unsigned short* __restrict__ wcat,
                                 unsigned short* __restrict__ zb, int N) {
    __shared__ __align__(16) unsigned short As[BM * BK];
    __shared__ __align__(16) unsigned short Bs[BN * BK];
    const int tid = threadIdx.x;
    const int wave = tid >> 6;
    const int lane = tid & 63;
    const int bm = blockIdx.x * BM;
    const int bn = blockIdx.y * BN;
    const int warpM = wave >> 1;   // 0..1
    const int warpN = wave & 1;    // 0..1
    const int l15 = lane & 15;
    const int quad = lane >> 4;

    float4v acc[4][4];
    #pragma unroll
    for (int i = 0; i < 4; ++i)
        #pragma unroll
        for (int j = 0; j < 4; ++j)
            acc[i][j] = (float4v){0.f, 0.f, 0.f, 0.f};

    for (int kt = 0; kt < D_IN / BK; ++kt) {
        #pragma unroll
        for (int iss = 0; iss < 2; ++iss) {
            const int pbase = iss * 256 + wave * 64;
            const int p = pbase + lane;
            const int m = p >> 2;
            const int g = (p & 3) ^ ((m >> 1) & 3);
            int gm = bm + m; if (gm >= N) gm = N - 1;
            async16(xb + (size_t)gm * D_IN + kt * BK + g * 8, &As[pbase * 8]);
            async16(wcat + (size_t)(bn + m) * D_IN + kt * BK + g * 8, &Bs[pbase * 8]);
        }
        __syncthreads();

        short8 af[4], bfr[4];
        #pragma unroll
        for (int mi = 0; mi < 4; ++mi) {
            int m = warpM * 64 + mi * 16 + l15;
            af[mi] = *(const short8*)&As[m * BK + (quad ^ ((m >> 1) & 3)) * 8];
        }
        #pragma unroll
        for (int ni = 0; ni < 4; ++ni) {
            int n = warpN * 64 + ni * 16 + l15;
            bfr[ni] = *(const short8*)&Bs[n * BK + (quad ^ ((n >> 1) & 3)) * 8];
        }
        #pragma unroll
        for (int mi = 0; mi < 4; ++mi)
            #pragma unroll
            for (int ni = 0; ni < 4; ++ni)
                acc[mi][ni] = __builtin_amdgcn_mfma_f32_16x16x32_bf16(af[mi], bfr[ni], acc[mi][ni], 0, 0, 0);
        __syncthreads();
    }

    // C/D layout: col = lane&15 (n), row = quad*4 + reg (m)
    #pragma unroll
    for (int mi = 0; mi < 4; ++mi) {
        #pragma unroll
        for (int reg = 0; reg < 4; ++reg) {
            int gm = bm + warpM * 64 + mi * 16 + quad * 4 + reg;
            if (gm < N) {
                #pragma unroll
                for (int ni = 0; ni < 4; ++ni) {
                    int gn = bn + warpN * 64 + ni * 16 + l15;
                    zb[(size_t)gm * D_IN + gn] = f2bf(acc[mi][ni][reg]);
                }
            }
        }
    }
}

// ---------------- gather: one wave per (node, dir), bf16 z ----------------

__global__ void gather_kernel(const unsigned short* __restrict__ zb, const int* __restrict__ adj,
                              const int* __restrict__ offs, const int* __restrict__ cnt,
                              const float* __restrict__ inv_in, const float* __restrict__ inv_out,
                              const float* __restrict__ bias,
                              float* __restrict__ out, int N) {
    const int wave = threadIdx.x >> 6;
    const int lane = threadIdx.x & 63;
    const int slot = blockIdx.x * 4 + wave;
    if (slot >= 2 * N) return;
    const int node = slot >> 1;
    const int dir = slot & 1;
    const int csr = dir * N + node;
    const int beg = offs[csr];
    const int end = beg + cnt[csr];
    const float* __restrict__ wv = dir ? inv_in : inv_out;
    const int choff = dir * D_HALF + 2 * lane;   // two channels per lane

    float a0 = 0.f, a1 = 0.f, b0 = 0.f, b1 = 0.f;
    int k = beg;
    for (; k + 1 < end; k += 2) {
        int n0 = adj[k], n1 = adj[k + 1];
        float w0 = wv[n0], w1 = wv[n1];
        unsigned u0 = *(const unsigned*)&zb[(size_t)n0 * D_IN + choff];
        unsigned u1 = *(const unsigned*)&zb[(size_t)n1 * D_IN + choff];
        a0 += w0 * bflo(u0); a1 += w0 * bfhi(u0);
        b0 += w1 * bflo(u1); b1 += w1 * bfhi(u1);
    }
    if (k < end) {
        int n0 = adj[k];
        float w0 = wv[n0];
        unsigned u0 = *(const unsigned*)&zb[(size_t)n0 * D_IN + choff];
        a0 += w0 * bflo(u0); a1 += w0 * bfhi(u0);
    }
    a0 += b0; a1 += b1;

    const float scale = dir ? inv_out[node] : inv_in[node];
    const float invprod = inv_in[node] * inv_out[node];
    unsigned us = *(const unsigned*)&zb[(size_t)node * D_IN + choff];
    size_t oi = (size_t)node * D_IN + choff;
    float2 o;
    o.x = bias[choff]     + invprod * bflo(us) + scale * a0;
    o.y = bias[choff + 1] + invprod * bfhi(us) + scale * a1;
    *(float2*)&out[oi] = o;
}

// ---------------- launch ----------------

extern "C" void kernel_launch(void* const* d_in, const int* in_sizes, int n_in,
                              void* d_out, int out_size, void* d_ws, size_t ws_size,
                              hipStream_t stream) {
    const float* x    = (const float*)d_in[0];
    const int*   ei   = (const int*)d_in[1];
    const float* Wf   = (const float*)d_in[2];
    const float* Wb   = (const float*)d_in[3];
    const float* bias = (const float*)d_in[4];
    float* out = (float*)d_out;

    const int N = in_sizes[0] / D_IN;
    const int E = in_sizes[1] / 2;
    const int* col = ei;
    const int* rowp = ei + E;

    // workspace (~121 MB)
    char* ws = (char*)d_ws;
    unsigned short* xb = (unsigned short*)ws;   ws += (size_t)N * D_IN * sizeof(short);
    unsigned short* zb = (unsigned short*)ws;   ws += (size_t)N * D_IN * sizeof(short);
    unsigned short* wcat = (unsigned short*)ws; ws += (size_t)2 * D_HALF * D_IN * sizeof(short);
    int* cnt = (int*)ws;            ws += (size_t)2 * N * sizeof(int);
    int* ctr = (int*)ws;            ws += (size_t)2 * N * sizeof(int);
    int* offs = (int*)ws;           ws += (size_t)2 * N * sizeof(int);
    float* inv_in = (float*)ws;     ws += (size_t)N * sizeof(float);
    float* inv_out = (float*)ws;    ws += (size_t)N * sizeof(float);
    int* adj = (int*)ws;            ws += (size_t)2 * E * sizeof(int);
    int* blksum = (int*)ws;         ws += 1024 * sizeof(int);
    int* gcnt = (int*)ws;           ws += FB_NB * sizeof(int);

    // staging aliases zb: zb (51.2 MB) is first written by the GEMM, which
    // runs after scatter_kernel in stream order; staging needs only 25.6 MB.
    uint2* staging = (uint2*)zb;

    const int M = 2 * N;
    const int nb = (M + 255) / 256;

    const int n4 = N * D_IN / 4;
    const int w4 = (2 * D_HALF * D_IN) / 4;
    cast_kernel<<<(n4 + w4 + 255) / 256, 256, 0, stream>>>(x, Wf, Wb, xb, wcat, n4);

    zero_kernel<<<(M + 255) / 256, 256, 0, stream>>>(cnt, ctr, gcnt, M);
    hist_kernel<<<(E + 255) / 256, 256, 0, stream>>>(col, rowp, cnt, N, E);
    inv_kernel<<<(N + 255) / 256, 256, 0, stream>>>(cnt, inv_in, inv_out, N);

    scan1_kernel<<<nb, 256, 0, stream>>>(cnt, offs, blksum, M);
    scan2_kernel<<<1, 1024, 0, stream>>>(blksum, nb);
    scan3_kernel<<<nb, 256, 0, stream>>>(offs, blksum, M);

    const int twoE = 2 * E;
    const int nbuck = (twoE + (1 << FB_SH) - 1) >> FB_SH;
    partition_kernel<<<(E + 2047) / 2048, 256, 0, stream>>>(col, rowp, offs, ctr, gcnt,
                                                            staging, N, E);
    scatter_kernel<<<nbuck, 256, 0, stream>>>(staging, adj, twoE);

    dim3 ggrid((N + BM - 1) / BM, D_IN / BN);
    gemm_mfma_kernel<<<ggrid, 256, 0, stream>>>(xb, wcat, zb, N);

    gather_kernel<<<(2 * N + 3) / 4, 256, 0, stream>>>(zb, adj, offs, cnt, inv_in, inv_out, bias, out, N);
}

// Round 2
// 676.317 us; speedup vs baseline: 1.0776x; 1.0776x over previous
//
#include <hip/hip_runtime.h>

#define D_IN 256
#define D_HALF 128

typedef __attribute__((ext_vector_type(8))) short short8;
typedef __attribute__((ext_vector_type(4))) float float4v;

__device__ __forceinline__ unsigned short f2bf(float f) {
    union { float f; unsigned u; } v; v.f = f;
    unsigned r = v.u + 0x7FFF + ((v.u >> 16) & 1);   // RNE
    return (unsigned short)(r >> 16);
}
__device__ __forceinline__ float bflo(unsigned u) { union { unsigned u; float f; } v; v.u = u << 16; return v.f; }
__device__ __forceinline__ float bfhi(unsigned u) { union { unsigned u; float f; } v; v.u = u & 0xffff0000u; return v.f; }

__device__ __forceinline__ void async16(const void* g, void* l) {
    __builtin_amdgcn_global_load_lds(
        (const __attribute__((address_space(1))) unsigned int*)g,
        (__attribute__((address_space(3))) unsigned int*)l, 16, 0, 0);
}

// ---------------- CSR build ----------------

#define FB_SH 14            // bucket = 16384 adj slots = 64 KB write window
#define FB_NB 512           // max buckets supported (2E <= 512*16384 = 8.4M)

__global__ void zero_kernel(int* __restrict__ cnt, int* __restrict__ ctr,
                            int* __restrict__ gcnt, int M) {
    int i = blockIdx.x * blockDim.x + threadIdx.x;
    if (i < M) { cnt[i] = 0; ctr[i] = 0; }
    if (i < FB_NB) gcnt[i] = 0;
}

__global__ void hist_kernel(const int* __restrict__ col, const int* __restrict__ row,
                            int* __restrict__ cnt, int N, int E) {
    int i = blockIdx.x * blockDim.x + threadIdx.x;
    if (i < E) {
        atomicAdd(&cnt[col[i]], 1);
        atomicAdd(&cnt[N + row[i]], 1);
    }
}

__global__ void inv_kernel(const int* __restrict__ cnt,
                           float* __restrict__ inv_in, float* __restrict__ inv_out, int N) {
    int i = blockIdx.x * blockDim.x + threadIdx.x;
    if (i < N) {
        inv_in[i]  = rsqrtf((float)(cnt[i] + 1));
        inv_out[i] = rsqrtf((float)(cnt[N + i] + 1));
    }
}

__global__ void scan1_kernel(const int* __restrict__ cnt, int* __restrict__ offs,
                             int* __restrict__ blksum, int M) {
    __shared__ int s[256];
    int i = blockIdx.x * 256 + threadIdx.x;
    int v = (i < M) ? cnt[i] : 0;
    s[threadIdx.x] = v;
    __syncthreads();
    for (int d = 1; d < 256; d <<= 1) {
        int t = (threadIdx.x >= d) ? s[threadIdx.x - d] : 0;
        __syncthreads();
        s[threadIdx.x] += t;
        __syncthreads();
    }
    if (i < M) offs[i] = s[threadIdx.x] - v;
    if (threadIdx.x == 255) blksum[blockIdx.x] = s[255];
}

__global__ void scan2_kernel(int* __restrict__ blksum, int nb) {
    __shared__ int s[1024];
    int v = (threadIdx.x < nb) ? blksum[threadIdx.x] : 0;
    s[threadIdx.x] = v;
    __syncthreads();
    for (int d = 1; d < 1024; d <<= 1) {
        int t = (threadIdx.x >= d) ? s[threadIdx.x - d] : 0;
        __syncthreads();
        s[threadIdx.x] += t;
        __syncthreads();
    }
    if (threadIdx.x < nb) blksum[threadIdx.x] = s[threadIdx.x] - v;
}

__global__ void scan3_kernel(int* __restrict__ offs, const int* __restrict__ blksum, int M) {
    int i = blockIdx.x * 256 + threadIdx.x;
    if (i < M) offs[i] += blksum[blockIdx.x];
}

// Pass A: compute (pos,val) scatter items, partition them into buckets of
// 16384 adj slots each via LDS histogram + block-aggregated global atomics.
// Staging layout is fixed: bucket b owns staging[b<<FB_SH .. (b+1)<<FB_SH)
// because every adj position in [0,2E) occurs exactly once.
// 1024 edges (2048 items) per block -> 782 blocks (~3 waves/SIMD of TLP
// to hide the returning-atomic latency; 2048/block was only 1.5 blk/CU).
__global__ void partition_kernel(const int* __restrict__ col, const int* __restrict__ row,
                                 const int* __restrict__ offs, int* __restrict__ ctr,
                                 int* __restrict__ gcnt, uint2* __restrict__ staging,
                                 int N, int E) {
    __shared__ int scnt[FB_NB];
    __shared__ int sbase[FB_NB];
    const int tid = threadIdx.x;
    #pragma unroll
    for (int b = 0; b < FB_NB / 256; ++b) scnt[b * 256 + tid] = 0;
    __syncthreads();

    int pos[8], val[8], rnk[8];
    const int base = blockIdx.x * 1024;
    #pragma unroll
    for (int j = 0; j < 4; ++j) {
        int e = base + j * 256 + tid;
        if (e < E) {
            int c = col[e], r = row[e];
            int pf = offs[c] + atomicAdd(&ctr[c], 1);
            int pb = offs[N + r] + atomicAdd(&ctr[N + r], 1);
            pos[2 * j]     = pf; val[2 * j]     = r;
            pos[2 * j + 1] = pb; val[2 * j + 1] = c;
        } else {
            pos[2 * j] = -1; pos[2 * j + 1] = -1;
        }
    }
    #pragma unroll
    for (int k = 0; k < 8; ++k)
        if (pos[k] >= 0) rnk[k] = atomicAdd(&scnt[pos[k] >> FB_SH], 1);
    __syncthreads();
    #pragma unroll
    for (int b = 0; b < FB_NB / 256; ++b) {
        int idx = b * 256 + tid;
        int c = scnt[idx];
        sbase[idx] = c ? atomicAdd(&gcnt[idx], c) : 0;
    }
    __syncthreads();
    #pragma unroll
    for (int k = 0; k < 8; ++k) {
        if (pos[k] >= 0) {
            int bk = pos[k] >> FB_SH;
            staging[((size_t)bk << FB_SH) + sbase[bk] + rnk[k]] =
                make_uint2((unsigned)pos[k], (unsigned)val[k]);
        }
    }
}

// Pass B: one block per bucket. Coalesced staging read; scatter writes are
// confined to this block's exclusive 64 KB adj window -> full-line writeback.
__global__ void scatter_kernel(const uint2* __restrict__ staging, int* __restrict__ adj,
                               int twoE) {
    const int start = blockIdx.x << FB_SH;
    const int cnt = min(1 << FB_SH, twoE - start);
    for (int i = threadIdx.x; i < cnt; i += 256) {
        uint2 it = staging[(size_t)start + i];
        adj[it.x] = (int)it.y;
    }
}

// ---------------- cast x -> bf16, [Wf;Wb] -> bf16 ----------------

__global__ void cast_kernel(const float* __restrict__ x, const float* __restrict__ Wf,
                            const float* __restrict__ Wb, unsigned short* __restrict__ xb,
                            unsigned short* __restrict__ wcat, int n4) {
    int i = blockIdx.x * blockDim.x + threadIdx.x;
    const int w4 = (2 * D_HALF * D_IN) / 4;  // 16384 float4s of Wcat
    if (i < n4) {
        float4 v = ((const float4*)x)[i];
        ushort4 o = { f2bf(v.x), f2bf(v.y), f2bf(v.z), f2bf(v.w) };
        ((ushort4*)xb)[i] = o;
    } else if (i < n4 + w4) {
        int j = i - n4;
        int elem = j * 4;
        const float* src = (elem < D_HALF * D_IN) ? (Wf + elem) : (Wb + (elem - D_HALF * D_IN));
        float4 v = *(const float4*)src;
        ushort4 o = { f2bf(v.x), f2bf(v.y), f2bf(v.z), f2bf(v.w) };
        ((ushort4*)wcat)[j] = o;
    }
}

// ---------------- bf16 MFMA GEMM: zb[m][n] = sum_k xb[m][k] * wcat[n][k] ----------------
// 128x128 tile, BK=32, 256 threads (4 waves, each 64x64), 16x16x32 MFMA.
// LDS XOR swizzle: granule (16B) of (row m, kgran g) stored at m*64B + (g ^ ((m>>1)&3))*16B.

#define BM 128
#define BN 128
#define BK 32

__global__ void gemm_mfma_kernel(const unsigned short* __restrict__ xb,
                                 const unsigned short* __restrict__ wcat,
                                 unsigned short* __restrict__ zb, int N) {
    __shared__ __align__(16) unsigned short As[BM * BK];
    __shared__ __align__(16) unsigned short Bs[BN * BK];
    const int tid = threadIdx.x;
    const int wave = tid >> 6;
    const int lane = tid & 63;
    const int bm = blockIdx.x * BM;
    const int bn = blockIdx.y * BN;
    const int warpM = wave >> 1;   // 0..1
    const int warpN = wave & 1;    // 0..1
    const int l15 = lane & 15;
    const int quad = lane >> 4;

    float4v acc[4][4];
    #pragma unroll
    for (int i = 0; i < 4; ++i)
        #pragma unroll
        for (int j = 0; j < 4; ++j)
            acc[i][j] = (float4v){0.f, 0.f, 0.f, 0.f};

    for (int kt = 0; kt < D_IN / BK; ++kt) {
        #pragma unroll
        for (int iss = 0; iss < 2; ++iss) {
            const int pbase = iss * 256 + wave * 64;
            const int p = pbase + lane;
            const int m = p >> 2;
            const int g = (p & 3) ^ ((m >> 1) & 3);
            int gm = bm + m; if (gm >= N) gm = N - 1;
            async16(xb + (size_t)gm * D_IN + kt * BK + g * 8, &As[pbase * 8]);
            async16(wcat + (size_t)(bn + m) * D_IN + kt * BK + g * 8, &Bs[pbase * 8]);
        }
        __syncthreads();

        short8 af[4], bfr[4];
        #pragma unroll
        for (int mi = 0; mi < 4; ++mi) {
            int m = warpM * 64 + mi * 16 + l15;
            af[mi] = *(const short8*)&As[m * BK + (quad ^ ((m >> 1) & 3)) * 8];
        }
        #pragma unroll
        for (int ni = 0; ni < 4; ++ni) {
            int n = warpN * 64 + ni * 16 + l15;
            bfr[ni] = *(const short8*)&Bs[n * BK + (quad ^ ((n >> 1) & 3)) * 8];
        }
        #pragma unroll
        for (int mi = 0; mi < 4; ++mi)
            #pragma unroll
            for (int ni = 0; ni < 4; ++ni)
                acc[mi][ni] = __builtin_amdgcn_mfma_f32_16x16x32_bf16(af[mi], bfr[ni], acc[mi][ni], 0, 0, 0);
        __syncthreads();
    }

    // C/D layout: col = lane&15 (n), row = quad*4 + reg (m)
    #pragma unroll
    for (int mi = 0; mi < 4; ++mi) {
        #pragma unroll
        for (int reg = 0; reg < 4; ++reg) {
            int gm = bm + warpM * 64 + mi * 16 + quad * 4 + reg;
            if (gm < N) {
                #pragma unroll
                for (int ni = 0; ni < 4; ++ni) {
                    int gn = bn + warpN * 64 + ni * 16 + l15;
                    zb[(size_t)gm * D_IN + gn] = f2bf(acc[mi][ni][reg]);
                }
            }
        }
    }
}

// ---------------- gather: one wave per (node, dir), bf16 z ----------------
// Lane-parallel index fetch: 64 adj entries + weights loaded with 2
// instructions, broadcast via v_readlane (SGPR base -> cheap addressing),
// 8 independent zb row loads in flight per unrolled group (MLP=8).
// Padded lanes (deg % 8) read the node's own row with weight 0 (L1 hit).

__global__ void gather_kernel(const unsigned short* __restrict__ zb, const int* __restrict__ adj,
                              const int* __restrict__ offs, const int* __restrict__ cnt,
                              const float* __restrict__ inv_in, const float* __restrict__ inv_out,
                              const float* __restrict__ bias,
                              float* __restrict__ out, int N) {
    const int wave = threadIdx.x >> 6;
    const int lane = threadIdx.x & 63;
    const int slot = blockIdx.x * 4 + wave;
    if (slot >= 2 * N) return;
    const int node = slot >> 1;
    const int dir = slot & 1;
    const int csr = dir * N + node;
    const int beg = offs[csr];
    const int deg = cnt[csr];
    const int end = beg + deg;
    const float* __restrict__ wv = dir ? inv_in : inv_out;
    const int choff = dir * D_HALF + 2 * lane;   // two channels per lane

    float a0 = 0.f, a1 = 0.f, b0 = 0.f, b1 = 0.f;
    for (int base = beg; base < end; base += 64) {
        int len = end - base; if (len > 64) len = 64;
        int nb = node; float w = 0.f;
        if (lane < len) {
            int t = adj[base + lane];
            nb = t;
            w = wv[t];
        }
        for (int j0 = 0; j0 < len; j0 += 8) {
            #pragma unroll
            for (int jj = 0; jj < 8; ++jj) {
                const int j = j0 + jj;
                int n0 = __builtin_amdgcn_readlane(nb, j);
                float w0 = __int_as_float(__builtin_amdgcn_readlane(__float_as_int(w), j));
                unsigned u0 = *(const unsigned*)&zb[(size_t)n0 * D_IN + choff];
                if (jj & 1) {
                    b0 = fmaf(w0, bflo(u0), b0);
                    b1 = fmaf(w0, bfhi(u0), b1);
                } else {
                    a0 = fmaf(w0, bflo(u0), a0);
                    a1 = fmaf(w0, bfhi(u0), a1);
                }
            }
        }
    }
    a0 += b0; a1 += b1;

    const float scale = dir ? inv_out[node] : inv_in[node];
    const float invprod = inv_in[node] * inv_out[node];
    unsigned us = *(const unsigned*)&zb[(size_t)node * D_IN + choff];
    size_t oi = (size_t)node * D_IN + choff;
    float2 o;
    o.x = bias[choff]     + invprod * bflo(us) + scale * a0;
    o.y = bias[choff + 1] + invprod * bfhi(us) + scale * a1;
    *(float2*)&out[oi] = o;
}

// ---------------- launch ----------------

extern "C" void kernel_launch(void* const* d_in, const int* in_sizes, int n_in,
                              void* d_out, int out_size, void* d_ws, size_t ws_size,
                              hipStream_t stream) {
    const float* x    = (const float*)d_in[0];
    const int*   ei   = (const int*)d_in[1];
    const float* Wf   = (const float*)d_in[2];
    const float* Wb   = (const float*)d_in[3];
    const float* bias = (const float*)d_in[4];
    float* out = (float*)d_out;

    const int N = in_sizes[0] / D_IN;
    const int E = in_sizes[1] / 2;
    const int* col = ei;
    const int* rowp = ei + E;

    // workspace (~121 MB)
    char* ws = (char*)d_ws;
    unsigned short* xb = (unsigned short*)ws;   ws += (size_t)N * D_IN * sizeof(short);
    unsigned short* zb = (unsigned short*)ws;   ws += (size_t)N * D_IN * sizeof(short);
    unsigned short* wcat = (unsigned short*)ws; ws += (size_t)2 * D_HALF * D_IN * sizeof(short);
    int* cnt = (int*)ws;            ws += (size_t)2 * N * sizeof(int);
    int* ctr = (int*)ws;            ws += (size_t)2 * N * sizeof(int);
    int* offs = (int*)ws;           ws += (size_t)2 * N * sizeof(int);
    float* inv_in = (float*)ws;     ws += (size_t)N * sizeof(float);
    float* inv_out = (float*)ws;    ws += (size_t)N * sizeof(float);
    int* adj = (int*)ws;            ws += (size_t)2 * E * sizeof(int);
    int* blksum = (int*)ws;         ws += 1024 * sizeof(int);
    int* gcnt = (int*)ws;           ws += FB_NB * sizeof(int);

    // staging aliases zb: zb (51.2 MB) is first written by the GEMM, which
    // runs after scatter_kernel in stream order; staging needs only 25.6 MB.
    uint2* staging = (uint2*)zb;

    const int M = 2 * N;
    const int nb = (M + 255) / 256;

    const int n4 = N * D_IN / 4;
    const int w4 = (2 * D_HALF * D_IN) / 4;
    cast_kernel<<<(n4 + w4 + 255) / 256, 256, 0, stream>>>(x, Wf, Wb, xb, wcat, n4);

    zero_kernel<<<(M + 255) / 256, 256, 0, stream>>>(cnt, ctr, gcnt, M);
    hist_kernel<<<(E + 255) / 256, 256, 0, stream>>>(col, rowp, cnt, N, E);
    inv_kernel<<<(N + 255) / 256, 256, 0, stream>>>(cnt, inv_in, inv_out, N);

    scan1_kernel<<<nb, 256, 0, stream>>>(cnt, offs, blksum, M);
    scan2_kernel<<<1, 1024, 0, stream>>>(blksum, nb);
    scan3_kernel<<<nb, 256, 0, stream>>>(offs, blksum, M);

    const int twoE = 2 * E;
    const int nbuck = (twoE + (1 << FB_SH) - 1) >> FB_SH;
    partition_kernel<<<(E + 1023) / 1024, 256, 0, stream>>>(col, rowp, offs, ctr, gcnt,
                                                            staging, N, E);
    scatter_kernel<<<nbuck, 256, 0, stream>>>(staging, adj, twoE);

    dim3 ggrid((N + BM - 1) / BM, D_IN / BN);
    gemm_mfma_kernel<<<ggrid, 256, 0, stream>>>(xb, wcat, zb, N);

    gather_kernel<<<(2 * N + 3) / 4, 256, 0, stream>>>(zb, adj, offs, cnt, inv_in, inv_out, bias, out, N);
}

// Round 3
// 531.875 us; speedup vs baseline: 1.3703x; 1.2716x over previous
//
#include <hip/hip_runtime.h>

#define D_IN 256
#define D_HALF 128

typedef __attribute__((ext_vector_type(8))) short short8;
typedef __attribute__((ext_vector_type(4))) float float4v;

__device__ __forceinline__ unsigned short f2bf(float f) {
    union { float f; unsigned u; } v; v.f = f;
    unsigned r = v.u + 0x7FFF + ((v.u >> 16) & 1);   // RNE
    return (unsigned short)(r >> 16);
}
__device__ __forceinline__ float bflo(unsigned u) { union { unsigned u; float f; } v; v.u = u << 16; return v.f; }
__device__ __forceinline__ float bfhi(unsigned u) { union { unsigned u; float f; } v; v.u = u & 0xffff0000u; return v.f; }

__device__ __forceinline__ void async16(const void* g, void* l) {
    __builtin_amdgcn_global_load_lds(
        (const __attribute__((address_space(1))) unsigned int*)g,
        (__attribute__((address_space(3))) unsigned int*)l, 16, 0, 0);
}

// ---------------- CSR build ----------------
// Two-stage bucket sort, NO per-item returning global atomics.
// Bucket = 512 consecutive csr slots (csr index = dir*N + node, M = 2N total).
// stagingBase[b] = offs[b*512] exactly, since offs is the scan of cnt.

#define S_SH 9               // 512 csr slots per bucket
#define NBK_MAX 512          // LDS histogram size (nbuck = ceil(M/512) <= 391)
#define CAP 12288            // items per bucket capacity: mean 8192, sigma ~90 -> +45 sigma
#define EPB 4096             // edges per p1 block

__global__ void zero_kernel(int* __restrict__ cnt, int* __restrict__ gcnt, int M) {
    int i = blockIdx.x * blockDim.x + threadIdx.x;
    if (i < M) cnt[i] = 0;
    if (i < NBK_MAX) gcnt[i] = 0;
}

__global__ void hist_kernel(const int* __restrict__ col, const int* __restrict__ row,
                            int* __restrict__ cnt, int N, int E) {
    int i = blockIdx.x * blockDim.x + threadIdx.x;
    if (i < E) {
        atomicAdd(&cnt[col[i]], 1);       // fire-and-forget
        atomicAdd(&cnt[N + row[i]], 1);
    }
}

__global__ void inv_kernel(const int* __restrict__ cnt,
                           float* __restrict__ inv_in, float* __restrict__ inv_out, int N) {
    int i = blockIdx.x * blockDim.x + threadIdx.x;
    if (i < N) {
        inv_in[i]  = rsqrtf((float)(cnt[i] + 1));
        inv_out[i] = rsqrtf((float)(cnt[N + i] + 1));
    }
}

__global__ void scan1_kernel(const int* __restrict__ cnt, int* __restrict__ offs,
                             int* __restrict__ blksum, int M) {
    __shared__ int s[256];
    int i = blockIdx.x * 256 + threadIdx.x;
    int v = (i < M) ? cnt[i] : 0;
    s[threadIdx.x] = v;
    __syncthreads();
    for (int d = 1; d < 256; d <<= 1) {
        int t = (threadIdx.x >= d) ? s[threadIdx.x - d] : 0;
        __syncthreads();
        s[threadIdx.x] += t;
        __syncthreads();
    }
    if (i < M) offs[i] = s[threadIdx.x] - v;
    if (threadIdx.x == 255) blksum[blockIdx.x] = s[255];
}

__global__ void scan2_kernel(int* __restrict__ blksum, int nb) {
    __shared__ int s[1024];
    int v = (threadIdx.x < nb) ? blksum[threadIdx.x] : 0;
    s[threadIdx.x] = v;
    __syncthreads();
    for (int d = 1; d < 1024; d <<= 1) {
        int t = (threadIdx.x >= d) ? s[threadIdx.x - d] : 0;
        __syncthreads();
        s[threadIdx.x] += t;
        __syncthreads();
    }
    if (threadIdx.x < nb) blksum[threadIdx.x] = s[threadIdx.x] - v;
}

__global__ void scan3_kernel(int* __restrict__ offs, const int* __restrict__ blksum, int M) {
    int i = blockIdx.x * 256 + threadIdx.x;
    if (i < M) offs[i] += blksum[blockIdx.x];
}

// Stage 1: partition (slot, nbr) items into node-range buckets.
// Phase 1: LDS histogram of this block's 2*EPB items.
// Then ONE returning atomic per (block, bucket) to claim a contiguous run.
// Phase 2: re-stream edges, rank via LDS atomic, write items into the run.
__global__ void p1_kernel(const int* __restrict__ col, const int* __restrict__ row,
                          const int* __restrict__ offs, int* __restrict__ gcnt,
                          uint2* __restrict__ staging, int N, int E) {
    __shared__ int hist[NBK_MAX];
    __shared__ int base_[NBK_MAX];
    const int tid = threadIdx.x;
    hist[tid] = 0; hist[tid + 256] = 0;
    __syncthreads();

    const int e0 = blockIdx.x * EPB;
    const int e1 = min(e0 + EPB, E);

    for (int e = e0 + tid; e < e1; e += 256) {
        int c = col[e], r = row[e];
        atomicAdd(&hist[c >> S_SH], 1);
        atomicAdd(&hist[(N + r) >> S_SH], 1);
    }
    __syncthreads();

    #pragma unroll
    for (int b = 0; b < NBK_MAX / 256; ++b) {
        int idx = b * 256 + tid;
        int c = hist[idx];
        if (c) base_[idx] = offs[idx << S_SH] + atomicAdd(&gcnt[idx], c);
    }
    __syncthreads();
    hist[tid] = 0; hist[tid + 256] = 0;
    __syncthreads();

    for (int e = e0 + tid; e < e1; e += 256) {
        int c = col[e], r = row[e];
        int bf = c >> S_SH;
        int rf = atomicAdd(&hist[bf], 1);
        staging[(size_t)base_[bf] + rf] = make_uint2((unsigned)c, (unsigned)r);
        int sb = N + r;
        int bb = sb >> S_SH;
        int rb = atomicAdd(&hist[bb], 1);
        staging[(size_t)base_[bb] + rb] = make_uint2((unsigned)sb, (unsigned)c);
    }
}

// Stage 2: one block per bucket. Slot bases come straight from offs (no scan).
// LDS-atomic rank -> LDS scatter -> fully coalesced contiguous adj write.
__global__ void bsort_kernel(const uint2* __restrict__ staging, const int* __restrict__ offs,
                             int* __restrict__ adj, int M, int twoE) {
    __shared__ int lbase[NBK_MAX];   // 512 local slot bases
    __shared__ int lcnt[NBK_MAX];
    __shared__ int lbuf[CAP];
    const int tid = threadIdx.x;
    const int s0 = blockIdx.x << S_SH;
    const int base = offs[s0];
    #pragma unroll
    for (int b = 0; b < 2; ++b) {
        int s = b * 256 + tid;
        int gs = s0 + s;
        lbase[s] = (gs < M) ? (offs[gs] - base) : 0;
        lcnt[s] = 0;
    }
    __syncthreads();
    const int end = (s0 + 512 >= M) ? twoE : offs[s0 + 512];
    const int count = end - base;

    for (int i = tid; i < count; i += 256) {
        uint2 it = staging[(size_t)base + i];
        int sl = (int)it.x - s0;
        int r = atomicAdd(&lcnt[sl], 1);
        lbuf[lbase[sl] + r] = (int)it.y;
    }
    __syncthreads();
    for (int i = tid; i < count; i += 256)
        adj[base + i] = lbuf[i];
}

// ---------------- cast x -> bf16, [Wf;Wb] -> bf16 ----------------

__global__ void cast_kernel(const float* __restrict__ x, const float* __restrict__ Wf,
                            const float* __restrict__ Wb, unsigned short* __restrict__ xb,
                            unsigned short* __restrict__ wcat, int n4) {
    int i = blockIdx.x * blockDim.x + threadIdx.x;
    const int w4 = (2 * D_HALF * D_IN) / 4;  // 16384 float4s of Wcat
    if (i < n4) {
        float4 v = ((const float4*)x)[i];
        ushort4 o = { f2bf(v.x), f2bf(v.y), f2bf(v.z), f2bf(v.w) };
        ((ushort4*)xb)[i] = o;
    } else if (i < n4 + w4) {
        int j = i - n4;
        int elem = j * 4;
        const float* src = (elem < D_HALF * D_IN) ? (Wf + elem) : (Wb + (elem - D_HALF * D_IN));
        float4 v = *(const float4*)src;
        ushort4 o = { f2bf(v.x), f2bf(v.y), f2bf(v.z), f2bf(v.w) };
        ((ushort4*)wcat)[j] = o;
    }
}

// ---------------- bf16 MFMA GEMM: zb[m][n] = sum_k xb[m][k] * wcat[n][k] ----------------
// 128x128 tile, BK=32, 256 threads (4 waves, each 64x64), 16x16x32 MFMA.
// LDS XOR swizzle: granule (16B) of (row m, kgran g) stored at m*64B + (g ^ ((m>>1)&3))*16B.

#define BM 128
#define BN 128
#define BK 32

__global__ void gemm_mfma_kernel(const unsigned short* __restrict__ xb,
                                 const unsigned short* __restrict__ wcat,
                                 unsigned short* __restrict__ zb, int N) {
    __shared__ __align__(16) unsigned short As[BM * BK];
    __shared__ __align__(16) unsigned short Bs[BN * BK];
    const int tid = threadIdx.x;
    const int wave = tid >> 6;
    const int lane = tid & 63;
    const int bm = blockIdx.x * BM;
    const int bn = blockIdx.y * BN;
    const int warpM = wave >> 1;   // 0..1
    const int warpN = wave & 1;    // 0..1
    const int l15 = lane & 15;
    const int quad = lane >> 4;

    float4v acc[4][4];
    #pragma unroll
    for (int i = 0; i < 4; ++i)
        #pragma unroll
        for (int j = 0; j < 4; ++j)
            acc[i][j] = (float4v){0.f, 0.f, 0.f, 0.f};

    for (int kt = 0; kt < D_IN / BK; ++kt) {
        #pragma unroll
        for (int iss = 0; iss < 2; ++iss) {
            const int pbase = iss * 256 + wave * 64;
            const int p = pbase + lane;
            const int m = p >> 2;
            const int g = (p & 3) ^ ((m >> 1) & 3);
            int gm = bm + m; if (gm >= N) gm = N - 1;
            async16(xb + (size_t)gm * D_IN + kt * BK + g * 8, &As[pbase * 8]);
            async16(wcat + (size_t)(bn + m) * D_IN + kt * BK + g * 8, &Bs[pbase * 8]);
        }
        __syncthreads();

        short8 af[4], bfr[4];
        #pragma unroll
        for (int mi = 0; mi < 4; ++mi) {
            int m = warpM * 64 + mi * 16 + l15;
            af[mi] = *(const short8*)&As[m * BK + (quad ^ ((m >> 1) & 3)) * 8];
        }
        #pragma unroll
        for (int ni = 0; ni < 4; ++ni) {
            int n = warpN * 64 + ni * 16 + l15;
            bfr[ni] = *(const short8*)&Bs[n * BK + (quad ^ ((n >> 1) & 3)) * 8];
        }
        #pragma unroll
        for (int mi = 0; mi < 4; ++mi)
            #pragma unroll
            for (int ni = 0; ni < 4; ++ni)
                acc[mi][ni] = __builtin_amdgcn_mfma_f32_16x16x32_bf16(af[mi], bfr[ni], acc[mi][ni], 0, 0, 0);
        __syncthreads();
    }

    // C/D layout: col = lane&15 (n), row = quad*4 + reg (m)
    #pragma unroll
    for (int mi = 0; mi < 4; ++mi) {
        #pragma unroll
        for (int reg = 0; reg < 4; ++reg) {
            int gm = bm + warpM * 64 + mi * 16 + quad * 4 + reg;
            if (gm < N) {
                #pragma unroll
                for (int ni = 0; ni < 4; ++ni) {
                    int gn = bn + warpN * 64 + ni * 16 + l15;
                    zb[(size_t)gm * D_IN + gn] = f2bf(acc[mi][ni][reg]);
                }
            }
        }
    }
}

// ---------------- gather: one wave per (node, dir), bf16 z ----------------
// Lane-parallel index fetch: 64 adj entries + weights loaded with 2
// instructions, broadcast via v_readlane (SGPR base -> cheap addressing),
// 8 independent zb row loads in flight per unrolled group (MLP=8).

__global__ void gather_kernel(const unsigned short* __restrict__ zb, const int* __restrict__ adj,
                              const int* __restrict__ offs, const int* __restrict__ cnt,
                              const float* __restrict__ inv_in, const float* __restrict__ inv_out,
                              const float* __restrict__ bias,
                              float* __restrict__ out, int N) {
    const int wave = threadIdx.x >> 6;
    const int lane = threadIdx.x & 63;
    const int slot = blockIdx.x * 4 + wave;
    if (slot >= 2 * N) return;
    const int node = slot >> 1;
    const int dir = slot & 1;
    const int csr = dir * N + node;
    const int beg = offs[csr];
    const int deg = cnt[csr];
    const int end = beg + deg;
    const float* __restrict__ wv = dir ? inv_in : inv_out;
    const int choff = dir * D_HALF + 2 * lane;   // two channels per lane

    float a0 = 0.f, a1 = 0.f, b0 = 0.f, b1 = 0.f;
    for (int base = beg; base < end; base += 64) {
        int len = end - base; if (len > 64) len = 64;
        int nb = node; float w = 0.f;
        if (lane < len) {
            int t = adj[base + lane];
            nb = t;
            w = wv[t];
        }
        for (int j0 = 0; j0 < len; j0 += 8) {
            #pragma unroll
            for (int jj = 0; jj < 8; ++jj) {
                const int j = j0 + jj;
                int n0 = __builtin_amdgcn_readlane(nb, j);
                float w0 = __int_as_float(__builtin_amdgcn_readlane(__float_as_int(w), j));
                unsigned u0 = *(const unsigned*)&zb[(size_t)n0 * D_IN + choff];
                if (jj & 1) {
                    b0 = fmaf(w0, bflo(u0), b0);
                    b1 = fmaf(w0, bfhi(u0), b1);
                } else {
                    a0 = fmaf(w0, bflo(u0), a0);
                    a1 = fmaf(w0, bfhi(u0), a1);
                }
            }
        }
    }
    a0 += b0; a1 += b1;

    const float scale = dir ? inv_out[node] : inv_in[node];
    const float invprod = inv_in[node] * inv_out[node];
    unsigned us = *(const unsigned*)&zb[(size_t)node * D_IN + choff];
    size_t oi = (size_t)node * D_IN + choff;
    float2 o;
    o.x = bias[choff]     + invprod * bflo(us) + scale * a0;
    o.y = bias[choff + 1] + invprod * bfhi(us) + scale * a1;
    *(float2*)&out[oi] = o;
}

// ---------------- launch ----------------

extern "C" void kernel_launch(void* const* d_in, const int* in_sizes, int n_in,
                              void* d_out, int out_size, void* d_ws, size_t ws_size,
                              hipStream_t stream) {
    const float* x    = (const float*)d_in[0];
    const int*   ei   = (const int*)d_in[1];
    const float* Wf   = (const float*)d_in[2];
    const float* Wb   = (const float*)d_in[3];
    const float* bias = (const float*)d_in[4];
    float* out = (float*)d_out;

    const int N = in_sizes[0] / D_IN;
    const int E = in_sizes[1] / 2;
    const int* col = ei;
    const int* rowp = ei + E;

    // workspace (~120 MB)
    char* ws = (char*)d_ws;
    unsigned short* xb = (unsigned short*)ws;   ws += (size_t)N * D_IN * sizeof(short);
    unsigned short* zb = (unsigned short*)ws;   ws += (size_t)N * D_IN * sizeof(short);
    unsigned short* wcat = (unsigned short*)ws; ws += (size_t)2 * D_HALF * D_IN * sizeof(short);
    int* cnt = (int*)ws;            ws += (size_t)2 * N * sizeof(int);
    int* offs = (int*)ws;           ws += (size_t)2 * N * sizeof(int);
    float* inv_in = (float*)ws;     ws += (size_t)N * sizeof(float);
    float* inv_out = (float*)ws;    ws += (size_t)N * sizeof(float);
    int* adj = (int*)ws;            ws += (size_t)2 * E * sizeof(int);
    int* blksum = (int*)ws;         ws += 1024 * sizeof(int);
    int* gcnt = (int*)ws;           ws += NBK_MAX * sizeof(int);

    // staging aliases zb: zb (51.2 MB) is first written by the GEMM, which
    // runs after bsort_kernel in stream order; staging needs only 25.6 MB.
    uint2* staging = (uint2*)zb;

    const int M = 2 * N;
    const int nb = (M + 255) / 256;

    const int n4 = N * D_IN / 4;
    const int w4 = (2 * D_HALF * D_IN) / 4;
    cast_kernel<<<(n4 + w4 + 255) / 256, 256, 0, stream>>>(x, Wf, Wb, xb, wcat, n4);

    zero_kernel<<<(M + 255) / 256, 256, 0, stream>>>(cnt, gcnt, M);
    hist_kernel<<<(E + 255) / 256, 256, 0, stream>>>(col, rowp, cnt, N, E);
    inv_kernel<<<(N + 255) / 256, 256, 0, stream>>>(cnt, inv_in, inv_out, N);

    scan1_kernel<<<nb, 256, 0, stream>>>(cnt, offs, blksum, M);
    scan2_kernel<<<1, 1024, 0, stream>>>(blksum, nb);
    scan3_kernel<<<nb, 256, 0, stream>>>(offs, blksum, M);

    const int twoE = 2 * E;
    const int nbuck = (M + 511) >> S_SH;
    p1_kernel<<<(E + EPB - 1) / EPB, 256, 0, stream>>>(col, rowp, offs, gcnt, staging, N, E);
    bsort_kernel<<<nbuck, 256, 0, stream>>>(staging, offs, adj, M, twoE);

    dim3 ggrid((N + BM - 1) / BM, D_IN / BN);
    gemm_mfma_kernel<<<ggrid, 256, 0, stream>>>(xb, wcat, zb, N);

    gather_kernel<<<(2 * N + 3) / 4, 256, 0, stream>>>(zb, adj, offs, cnt, inv_in, inv_out, bias, out, N);
}

// Round 4
// 395.706 us; speedup vs baseline: 1.8419x; 1.3441x over previous
//
#include <hip/hip_runtime.h>

#define D_IN 256
#define D_HALF 128

typedef __attribute__((ext_vector_type(8))) short short8;
typedef __attribute__((ext_vector_type(4))) float float4v;

__device__ __forceinline__ unsigned short f2bf(float f) {
    union { float f; unsigned u; } v; v.f = f;
    unsigned r = v.u + 0x7FFF + ((v.u >> 16) & 1);   // RNE
    return (unsigned short)(r >> 16);
}
__device__ __forceinline__ float bflo(unsigned u) { union { unsigned u; float f; } v; v.u = u << 16; return v.f; }
__device__ __forceinline__ float bfhi(unsigned u) { union { unsigned u; float f; } v; v.u = u & 0xffff0000u; return v.f; }

__device__ __forceinline__ void async16(const void* g, void* l) {
    __builtin_amdgcn_global_load_lds(
        (const __attribute__((address_space(1))) unsigned int*)g,
        (__attribute__((address_space(3))) unsigned int*)l, 16, 0, 0);
}

// ---------------- CSR build ----------------
// Fixed-capacity bucket sort. No global histogram, no global scan over M,
// no per-item returning atomics. Bucket = 512 consecutive csr slots.
// Item packed in u32: (slot_local << 23) | nbr   (needs N < 2^23).

#define S_SH 9               // 512 csr slots per bucket
#define NBK_MAX 512          // max buckets (M <= 512*512 = 262144)
#define CAP 12288            // items per bucket capacity (mean 8184, sigma ~90)
#define EPB 4096             // edges per p1 block (16 per thread)

__global__ void zero_kernel(int* __restrict__ gcnt) {
    int i = blockIdx.x * blockDim.x + threadIdx.x;
    if (i < NBK_MAX) gcnt[i] = 0;
}

// Stream edges once (held in registers), LDS histogram by bucket, ONE
// returning atomic per (block,bucket) to claim a run in the bucket's fixed
// region, then write packed items.
__global__ void p1_kernel(const int* __restrict__ col, const int* __restrict__ row,
                          int* __restrict__ gcnt, unsigned* __restrict__ staging,
                          int N, int E) {
    __shared__ int hist[NBK_MAX];
    __shared__ int base_[NBK_MAX];
    const int tid = threadIdx.x;
    hist[tid] = 0; hist[tid + 256] = 0;
    __syncthreads();

    int ce[16], re[16];
    const int e0 = blockIdx.x * EPB;
    #pragma unroll
    for (int j = 0; j < 16; ++j) {
        int e = e0 + j * 256 + tid;
        if (e < E) {
            ce[j] = col[e];
            re[j] = row[e];
            atomicAdd(&hist[ce[j] >> S_SH], 1);
            atomicAdd(&hist[(N + re[j]) >> S_SH], 1);
        } else {
            ce[j] = -1; re[j] = 0;
        }
    }
    __syncthreads();

    #pragma unroll
    for (int b = 0; b < NBK_MAX / 256; ++b) {
        int idx = b * 256 + tid;
        int c = hist[idx];
        if (c) base_[idx] = idx * CAP + atomicAdd(&gcnt[idx], c);
    }
    __syncthreads();
    hist[tid] = 0; hist[tid + 256] = 0;
    __syncthreads();

    #pragma unroll
    for (int j = 0; j < 16; ++j) {
        if (ce[j] >= 0) {
            int c = ce[j], r = re[j];
            int bf = c >> S_SH;
            int rf = atomicAdd(&hist[bf], 1);
            staging[(size_t)base_[bf] + rf] = ((unsigned)(c & 511) << 23) | (unsigned)r;
            int sb = N + r;
            int bb = sb >> S_SH;
            int rb = atomicAdd(&hist[bb], 1);
            staging[(size_t)base_[bb] + rb] = ((unsigned)(sb & 511) << 23) | (unsigned)c;
        }
    }
}

// Exclusive scan of per-bucket totals -> global bucket bases. 1 block.
__global__ void scanB_kernel(const int* __restrict__ gcnt, int* __restrict__ bbase, int nbuck) {
    __shared__ int s[NBK_MAX];
    const int tid = threadIdx.x;
    int v = (tid < nbuck) ? gcnt[tid] : 0;
    s[tid] = v;
    __syncthreads();
    for (int d = 1; d < NBK_MAX; d <<= 1) {
        int t = (tid >= d) ? s[tid - d] : 0;
        __syncthreads();
        s[tid] += t;
        __syncthreads();
    }
    if (tid < nbuck) bbase[tid] = s[tid] - v;
}

// One block per bucket: LDS histogram over its 512 slots, LDS pair-scan ->
// per-slot counts & offsets (written to global cnt/offs), rank+scatter into
// LDS, fully coalesced contiguous adj write.
__global__ void bsort_kernel(const unsigned* __restrict__ staging, const int* __restrict__ gcnt,
                             const int* __restrict__ bbase, int* __restrict__ cnt,
                             int* __restrict__ offs, int* __restrict__ adj, int M) {
    __shared__ int lcnt[NBK_MAX];
    __shared__ int s[256];
    __shared__ int lbuf[CAP];
    const int tid = threadIdx.x;
    const int b = blockIdx.x;
    const int s0 = b << S_SH;
    lcnt[tid] = 0; lcnt[tid + 256] = 0;
    __syncthreads();

    const int count = gcnt[b];
    const int base = bbase[b];
    const unsigned* __restrict__ st = staging + (size_t)b * CAP;

    for (int i = tid; i < count; i += 256)
        atomicAdd(&lcnt[st[i] >> 23], 1);
    __syncthreads();

    // pair-scan: thread t owns slots 2t, 2t+1
    int v0 = lcnt[2 * tid], v1 = lcnt[2 * tid + 1];
    int pair = v0 + v1;
    s[tid] = pair;
    __syncthreads();
    for (int d = 1; d < 256; d <<= 1) {
        int t = (tid >= d) ? s[tid - d] : 0;
        __syncthreads();
        s[tid] += t;
        __syncthreads();
    }
    int excl = s[tid] - pair;

    int gs0 = s0 + 2 * tid;
    if (gs0 < M)     { cnt[gs0] = v0;     offs[gs0] = base + excl; }
    if (gs0 + 1 < M) { cnt[gs0 + 1] = v1; offs[gs0 + 1] = base + excl + v0; }

    // reuse lcnt as running positions
    lcnt[2 * tid] = excl;
    lcnt[2 * tid + 1] = excl + v0;
    __syncthreads();

    for (int i = tid; i < count; i += 256) {
        unsigned it = st[i];
        int sl = it >> 23;
        int p = atomicAdd(&lcnt[sl], 1);
        lbuf[p] = (int)(it & 0x7fffffu);
    }
    __syncthreads();
    for (int i = tid; i < count; i += 256)
        adj[base + i] = lbuf[i];
}

__global__ void inv_kernel(const int* __restrict__ cnt,
                           float* __restrict__ inv_in, float* __restrict__ inv_out, int N) {
    int i = blockIdx.x * blockDim.x + threadIdx.x;
    if (i < N) {
        inv_in[i]  = rsqrtf((float)(cnt[i] + 1));
        inv_out[i] = rsqrtf((float)(cnt[N + i] + 1));
    }
}

// ---------------- cast x -> bf16, [Wf;Wb] -> bf16 ----------------

__global__ void cast_kernel(const float* __restrict__ x, const float* __restrict__ Wf,
                            const float* __restrict__ Wb, unsigned short* __restrict__ xb,
                            unsigned short* __restrict__ wcat, int n4) {
    int i = blockIdx.x * blockDim.x + threadIdx.x;
    const int w4 = (2 * D_HALF * D_IN) / 4;  // 16384 float4s of Wcat
    if (i < n4) {
        float4 v = ((const float4*)x)[i];
        ushort4 o = { f2bf(v.x), f2bf(v.y), f2bf(v.z), f2bf(v.w) };
        ((ushort4*)xb)[i] = o;
    } else if (i < n4 + w4) {
        int j = i - n4;
        int elem = j * 4;
        const float* src = (elem < D_HALF * D_IN) ? (Wf + elem) : (Wb + (elem - D_HALF * D_IN));
        float4 v = *(const float4*)src;
        ushort4 o = { f2bf(v.x), f2bf(v.y), f2bf(v.z), f2bf(v.w) };
        ((ushort4*)wcat)[j] = o;
    }
}

// ---------------- bf16 MFMA GEMM with pre-scaled epilogue ----------------
// zb[m][n] = f2bf( (sum_k xb[m][k]*wcat[n][k]) * s[m] )
// where s[m] = inv_out[m] for the forward half (blockIdx.y==0),
//       s[m] = inv_in[m]  for the backward half (blockIdx.y==1).
// This folds the per-SOURCE norm factor into zb so the gather needs no
// per-neighbor weight gather at all.

#define BM 128
#define BN 128
#define BK 32

__global__ void gemm_mfma_kernel(const unsigned short* __restrict__ xb,
                                 const unsigned short* __restrict__ wcat,
                                 const float* __restrict__ inv_in,
                                 const float* __restrict__ inv_out,
                                 unsigned short* __restrict__ zb, int N) {
    __shared__ __align__(16) unsigned short As[BM * BK];
    __shared__ __align__(16) unsigned short Bs[BN * BK];
    const int tid = threadIdx.x;
    const int wave = tid >> 6;
    const int lane = tid & 63;
    const int bm = blockIdx.x * BM;
    const int bn = blockIdx.y * BN;
    const int warpM = wave >> 1;   // 0..1
    const int warpN = wave & 1;    // 0..1
    const int l15 = lane & 15;
    const int quad = lane >> 4;

    float4v acc[4][4];
    #pragma unroll
    for (int i = 0; i < 4; ++i)
        #pragma unroll
        for (int j = 0; j < 4; ++j)
            acc[i][j] = (float4v){0.f, 0.f, 0.f, 0.f};

    for (int kt = 0; kt < D_IN / BK; ++kt) {
        #pragma unroll
        for (int iss = 0; iss < 2; ++iss) {
            const int pbase = iss * 256 + wave * 64;
            const int p = pbase + lane;
            const int m = p >> 2;
            const int g = (p & 3) ^ ((m >> 1) & 3);
            int gm = bm + m; if (gm >= N) gm = N - 1;
            async16(xb + (size_t)gm * D_IN + kt * BK + g * 8, &As[pbase * 8]);
            async16(wcat + (size_t)(bn + m) * D_IN + kt * BK + g * 8, &Bs[pbase * 8]);
        }
        __syncthreads();

        short8 af[4], bfr[4];
        #pragma unroll
        for (int mi = 0; mi < 4; ++mi) {
            int m = warpM * 64 + mi * 16 + l15;
            af[mi] = *(const short8*)&As[m * BK + (quad ^ ((m >> 1) & 3)) * 8];
        }
        #pragma unroll
        for (int ni = 0; ni < 4; ++ni) {
            int n = warpN * 64 + ni * 16 + l15;
            bfr[ni] = *(const short8*)&Bs[n * BK + (quad ^ ((n >> 1) & 3)) * 8];
        }
        #pragma unroll
        for (int mi = 0; mi < 4; ++mi)
            #pragma unroll
            for (int ni = 0; ni < 4; ++ni)
                acc[mi][ni] = __builtin_amdgcn_mfma_f32_16x16x32_bf16(af[mi], bfr[ni], acc[mi][ni], 0, 0, 0);
        __syncthreads();
    }

    const float* __restrict__ sc = (blockIdx.y == 0) ? inv_out : inv_in;
    // C/D layout: col = lane&15 (n), row = quad*4 + reg (m)
    #pragma unroll
    for (int mi = 0; mi < 4; ++mi) {
        #pragma unroll
        for (int reg = 0; reg < 4; ++reg) {
            int gm = bm + warpM * 64 + mi * 16 + quad * 4 + reg;
            if (gm < N) {
                float s = sc[gm];
                #pragma unroll
                for (int ni = 0; ni < 4; ++ni) {
                    int gn = bn + warpN * 64 + ni * 16 + l15;
                    zb[(size_t)gm * D_IN + gn] = f2bf(acc[mi][ni][reg] * s);
                }
            }
        }
    }
}

// ---------------- gather: one wave per (node, dir), pre-scaled bf16 z ----
// zb rows are already scaled by the per-source norm factor, so the gather
// is a pure masked sum of rows (self row included), finished by one
// per-target scale. No per-neighbor weight gather, shorter latency chain.

__global__ void gather_kernel(const unsigned short* __restrict__ zb, const int* __restrict__ adj,
                              const int* __restrict__ offs, const int* __restrict__ cnt,
                              const float* __restrict__ inv_in, const float* __restrict__ inv_out,
                              const float* __restrict__ bias,
                              float* __restrict__ out, int N) {
    const int wave = threadIdx.x >> 6;
    const int lane = threadIdx.x & 63;
    const int slot = blockIdx.x * 4 + wave;
    if (slot >= 2 * N) return;
    const int node = slot >> 1;
    const int dir = slot & 1;
    const int csr = dir * N + node;
    const int beg = offs[csr];
    const int deg = cnt[csr];
    const int end = beg + deg;
    const int choff = dir * D_HALF + 2 * lane;   // two channels per lane

    float a0 = 0.f, a1 = 0.f, b0 = 0.f, b1 = 0.f;
    for (int base = beg; base < end; base += 64) {
        int len = end - base; if (len > 64) len = 64;
        int nb = (lane < len) ? adj[base + lane] : node;
        for (int j0 = 0; j0 < len; j0 += 8) {
            #pragma unroll
            for (int jj = 0; jj < 8; ++jj) {
                const int j = j0 + jj;
                float m = (j < len) ? 1.0f : 0.0f;   // wave-uniform mask
                int n0 = __builtin_amdgcn_readlane(nb, j);
                unsigned u0 = *(const unsigned*)&zb[(size_t)n0 * D_IN + choff];
                if (jj & 1) {
                    b0 = fmaf(m, bflo(u0), b0);
                    b1 = fmaf(m, bfhi(u0), b1);
                } else {
                    a0 = fmaf(m, bflo(u0), a0);
                    a1 = fmaf(m, bfhi(u0), a1);
                }
            }
        }
    }
    // self row (pre-scaled like every other row)
    unsigned us = *(const unsigned*)&zb[(size_t)node * D_IN + choff];
    a0 += b0 + bflo(us);
    a1 += b1 + bfhi(us);

    const float scale = dir ? inv_out[node] : inv_in[node];
    size_t oi = (size_t)node * D_IN + choff;
    float2 o;
    o.x = bias[choff]     + scale * a0;
    o.y = bias[choff + 1] + scale * a1;
    *(float2*)&out[oi] = o;
}

// ---------------- launch ----------------

extern "C" void kernel_launch(void* const* d_in, const int* in_sizes, int n_in,
                              void* d_out, int out_size, void* d_ws, size_t ws_size,
                              hipStream_t stream) {
    const float* x    = (const float*)d_in[0];
    const int*   ei   = (const int*)d_in[1];
    const float* Wf   = (const float*)d_in[2];
    const float* Wb   = (const float*)d_in[3];
    const float* bias = (const float*)d_in[4];
    float* out = (float*)d_out;

    const int N = in_sizes[0] / D_IN;
    const int E = in_sizes[1] / 2;
    const int* col = ei;
    const int* rowp = ei + E;

    // workspace
    char* ws = (char*)d_ws;
    unsigned short* xb = (unsigned short*)ws;   ws += (size_t)N * D_IN * sizeof(short);
    unsigned short* zb = (unsigned short*)ws;   ws += (size_t)N * D_IN * sizeof(short);
    unsigned short* wcat = (unsigned short*)ws; ws += (size_t)2 * D_HALF * D_IN * sizeof(short);
    int* cnt = (int*)ws;            ws += (size_t)2 * N * sizeof(int);
    int* offs = (int*)ws;           ws += (size_t)2 * N * sizeof(int);
    float* inv_in = (float*)ws;     ws += (size_t)N * sizeof(float);
    float* inv_out = (float*)ws;    ws += (size_t)N * sizeof(float);
    int* adj = (int*)ws;            ws += (size_t)2 * E * sizeof(int);
    int* gcnt = (int*)ws;           ws += NBK_MAX * sizeof(int);
    int* bbase = (int*)ws;          ws += NBK_MAX * sizeof(int);

    // staging aliases zb: zb (51.2 MB) is first written by the GEMM, which
    // runs after bsort_kernel in stream order; staging needs 391*CAP*4 = 19.2 MB.
    unsigned* staging = (unsigned*)zb;

    const int M = 2 * N;
    const int nbuck = (M + 511) >> S_SH;

    const int n4 = N * D_IN / 4;
    const int w4 = (2 * D_HALF * D_IN) / 4;
    cast_kernel<<<(n4 + w4 + 255) / 256, 256, 0, stream>>>(x, Wf, Wb, xb, wcat, n4);

    zero_kernel<<<2, 256, 0, stream>>>(gcnt);
    p1_kernel<<<(E + EPB - 1) / EPB, 256, 0, stream>>>(col, rowp, gcnt, staging, N, E);
    scanB_kernel<<<1, NBK_MAX, 0, stream>>>(gcnt, bbase, nbuck);
    bsort_kernel<<<nbuck, 256, 0, stream>>>(staging, gcnt, bbase, cnt, offs, adj, M);
    inv_kernel<<<(N + 255) / 256, 256, 0, stream>>>(cnt, inv_in, inv_out, N);

    dim3 ggrid((N + BM - 1) / BM, D_IN / BN);
    gemm_mfma_kernel<<<ggrid, 256, 0, stream>>>(xb, wcat, inv_in, inv_out, zb, N);

    gather_kernel<<<(2 * N + 3) / 4, 256, 0, stream>>>(zb, adj, offs, cnt, inv_in, inv_out, bias, out, N);
}